// Round 4
// baseline (120.020 us; speedup 1.0000x reference)
//
#include <hip/hip_runtime.h>
#include <hip/hip_bf16.h>

// MoE conv via bf16 MFMA implicit GEMM, tap-decomposed — T3/T4 LDS weight pipe.
// x: [32,64,64,64] f32  idx: [32] i32  Wc: [4,128,64,3,3] f32  bc: [4,128] f32
// out: [32,128,64,64] f32
//
// Pre-kernel: LDS-transpose reorder (R2, ~4 us). Layout [e][tap][ich8][oc128][icl8].
//
// Main: 1024 blocks x 256 thr (4 waves) = 2 output rows x 128 oc x 64 px.
// R1/R2 regression root-caused: per-lane GLOBAL weight loads with depth-1
// prefetch = ~32 cyc MFMA cover vs 400-900 cyc latency + 295 MB of L1 traffic
// (every wave re-reads the 144 KB e-slice). Fix: weights staged in LDS via
// global_load_lds DMA, double-buffered per tap, COUNTED vmcnt(4) so next-tap
// loads stay in flight across the barrier (T4) — no reg round-trip (R0's
// flaw), no vmcnt(0) drain in the main loop. 2 barriers/tap (buffer-reuse
// safety, m201 template). LDS 67 KB -> 2 blocks/CU = 8 waves/CU; weight reads
// now hit the separate 128 B/cyc LDS port instead of contending on L1.
// T1 XCD swizzle kept; T5 setprio around the MFMA cluster kept.
//
// (Round-3 resubmission: R2 bench failed with GPUAcquisitionTimeout — no data.)

#define IC 64
#define OC 128
#define HH 64
#define WW 64

typedef short short8 __attribute__((ext_vector_type(8)));
typedef ushort ushort8 __attribute__((ext_vector_type(8)));
typedef float float16 __attribute__((ext_vector_type(16)));

typedef const __attribute__((address_space(1))) void gas_t;
typedef __attribute__((address_space(3))) void las_t;

static __device__ __forceinline__ ushort f2bf(float v) {
    __hip_bfloat16 h = __float2bfloat16(v);
    return *(ushort*)&h;
}

// ---------------- pre-kernel: reorder + convert weights ----------------
// Block = (e, oc-group of 4). Phase 1: contiguous read of 2304 floats
// (coalesced), bf16 into LDS [ocl][ic*9+tap] with row pad 576->584. Phase 2:
// 288 ushort8 chunks, 8 LDS gathers each, coalesced 16B stores.
__global__ __launch_bounds__(256)
void reorder_w(const float* __restrict__ Wc, ushort* __restrict__ wout) {
    __shared__ ushort lw[4 * 584];          // 4672 B
    const int t   = threadIdx.x;
    const int e   = blockIdx.x >> 5;        // 0..3
    const int oc0 = (blockIdx.x & 31) * 4;  // 0,4,..,124
    const float* src = Wc + (size_t)(e * 128 + oc0) * 576;
#pragma unroll
    for (int k = 0; k < 9; ++k) {           // 9*256 = 2304 floats
        const int f   = k * 256 + t;
        const int ocl = f / 576;
        const int rem = f - ocl * 576;      // ic*9 + tap
        lw[ocl * 584 + rem] = f2bf(src[f]);
    }
    __syncthreads();
#pragma unroll
    for (int k = 0; k < 2; ++k) {
        const int n = k * 256 + t;          // 0..287 = tap(9) x ich(8) x ocl(4)
        if (n < 288) {
            const int ocl = n & 3, ich = (n >> 2) & 7, tap = n >> 5;
            ushort8 v;
#pragma unroll
            for (int icl = 0; icl < 8; ++icl)
                v[icl] = lw[ocl * 584 + (ich * 8 + icl) * 9 + tap];
            *(ushort8*)(wout +
                ((((size_t)(e * 9 + tap) * 8 + ich) * 128 + oc0 + ocl) * 8)) = v;
        }
    }
}

// ---------------- main kernel ----------------
__global__ __launch_bounds__(256, 4)
void moe_conv_mfma(const float* __restrict__ x, const int* __restrict__ idx,
                   const ushort* __restrict__ wre, const float* __restrict__ bc,
                   float* __restrict__ out) {
    __shared__ __align__(16) ushort xs[4 * 8 * 66 * 8];  // [r][ich][hc][icl] 33792 B
    __shared__ __align__(16) ushort wbuf[2][8192];       // tap dbuf, 2x16 KB
    __shared__ float bias[128];

    const int t = threadIdx.x;

    // T1: XCD c (= lin%8) owns contiguous work ids -> 4 whole samples per XCD.
    const int lin = blockIdx.x;                 // 0..1023
    const int nw  = (lin & 7) * 128 + (lin >> 3);
    const int b   = nw >> 5;                    // sample 0..31
    const int rp  = nw & 31;                    // row pair 0..31
    const int row0 = rp * 2;
    const int e    = ((unsigned)idx[b]) & 3;    // hardened expert index

    // --- per-lane MFMA coordinates ---
    const int lane31 = t & 31;
    const int lane64 = t & 63;
    const int lhi    = (t >> 5) & 1;
    const int wv     = t >> 6;            // 0..3
    const int w0     = wv & 1;            // oc half
    const int pr     = wv >> 1;           // output row within pair, 0..1

    const ushort* we = wre + (size_t)e * 9 * 8192;   // e-slice: 73,728 bf16

    // --- issue tap-0 DMA now: flies under the whole x-staging phase ---
    // Per wave: 4 x global_load_lds(16B) = 4 KB quarter of the 16 KB tap slice.
    // LDS dest is wave-uniform base + lane*16 (linear, matches wre order).
#pragma unroll
    for (int i = 0; i < 4; ++i) {
        __builtin_amdgcn_global_load_lds(
            (gas_t*)(we + wv * 2048 + i * 512 + lane64 * 8),
            (las_t*)&wbuf[0][wv * 2048 + i * 512], 16, 0, 0);
    }

    // --- halo-column zeros (hc = 0, 65) + bias stage ---
    if (t < 128) {  // r(4) x ich(8) x side(2) x q(2)
        const int r = t >> 5, rem = t & 31;
        const int ich = rem >> 2, side = (rem >> 1) & 1, q = rem & 1;
        const int hc = side ? 65 : 0;
        ushort4 z = {0, 0, 0, 0};
        *(ushort4*)&xs[(((r * 8 + ich) * 66 + hc) * 8 + q * 4)] = z;
    } else {
        bias[t - 128] = bc[e * OC + (t - 128)];
    }

    // --- x staging: fp32 [ic][h][w] -> bf16 [r(4)][ich][hc][icl] ---
    const float* xb = x + (size_t)b * IC * HH * WW;
    {
        const int gc   = t & 63;          // coalesced lane = w
        const int csel = t >> 6;          // 0..3
#pragma unroll
        for (int it = 0; it < 16; ++it) {
            const int combo = it * 4 + csel;       // 0..63 = r(4) x ich(8) x q(2)
            const int r = combo >> 4, rem = combo & 15;
            const int ich = rem >> 1, q = rem & 1;
            const int gr = row0 - 1 + r;
            ushort4 u = {0, 0, 0, 0};
            if ((unsigned)gr < (unsigned)HH) {
                const int ic0 = ich * 8 + q * 4;
                u.x = f2bf(xb[((ic0 + 0) * HH + gr) * WW + gc]);
                u.y = f2bf(xb[((ic0 + 1) * HH + gr) * WW + gc]);
                u.z = f2bf(xb[((ic0 + 2) * HH + gr) * WW + gc]);
                u.w = f2bf(xb[((ic0 + 3) * HH + gr) * WW + gc]);
            }
            *(ushort4*)&xs[(((r * 8 + ich) * 66 + (gc + 1)) * 8 + q * 4)] = u;
        }
    }

    float16 acc[2][2];
#pragma unroll
    for (int a = 0; a < 2; ++a)
#pragma unroll
        for (int cg = 0; cg < 2; ++cg)
#pragma unroll
            for (int r = 0; r < 16; ++r) acc[a][cg][r] = 0.0f;

    // Lane-constant part of the xs B-fragment address.
    const int xbase = ((pr * 8 + lhi) * 66 + lane31) * 8;

    // --- 9-tap pipeline: issue tap+1 DMA, counted vmcnt, barrier, MFMA, barrier
#pragma unroll
    for (int tap = 0; tap < 9; ++tap) {
        const int cur = tap & 1;
        if (tap < 8) {
            const ushort* wt = we + (tap + 1) * 8192;
#pragma unroll
            for (int i = 0; i < 4; ++i) {
                __builtin_amdgcn_global_load_lds(
                    (gas_t*)(wt + wv * 2048 + i * 512 + lane64 * 8),
                    (las_t*)&wbuf[cur ^ 1][wv * 2048 + i * 512], 16, 0, 0);
            }
            // wait own tap-DMAs (4 newer = tap+1's stay in flight);
            // lgkmcnt(0): xs staging ds_writes visible (tap 0), no-op later
            asm volatile("s_waitcnt vmcnt(4) lgkmcnt(0)" ::: "memory");
        } else {
            asm volatile("s_waitcnt vmcnt(0) lgkmcnt(0)" ::: "memory");
        }
        __builtin_amdgcn_s_barrier();   // all waves' tap data landed; xs ready

        const int kh = tap / 3;
        const int kw = tap - kh * 3;
        const int off = ((kh * 8) * 66 + kw) * 8;   // + ks*2*66*8 per step

        __builtin_amdgcn_s_setprio(1);
#pragma unroll
        for (int ks = 0; ks < 4; ++ks) {
            const int ich = ks * 2 + lhi;
            const short8 a0 = *(const short8*)&wbuf[cur][(ich * 128 + w0 * 64 + lane31) * 8];
            const short8 a1 = *(const short8*)&wbuf[cur][(ich * 128 + w0 * 64 + 32 + lane31) * 8];
            const short8 b0 = *(const short8*)&xs[xbase + off + ks * 2 * 66 * 8];
            const short8 b1 = *(const short8*)&xs[xbase + off + ks * 2 * 66 * 8 + 256];
            acc[0][0] = __builtin_amdgcn_mfma_f32_32x32x16_bf16(a0, b0, acc[0][0], 0, 0, 0);
            acc[0][1] = __builtin_amdgcn_mfma_f32_32x32x16_bf16(a0, b1, acc[0][1], 0, 0, 0);
            acc[1][0] = __builtin_amdgcn_mfma_f32_32x32x16_bf16(a1, b0, acc[1][0], 0, 0, 0);
            acc[1][1] = __builtin_amdgcn_mfma_f32_32x32x16_bf16(a1, b1, acc[1][1], 0, 0, 0);
        }
        __builtin_amdgcn_s_setprio(0);

        __builtin_amdgcn_s_barrier();   // buf[cur^1] reads done before tap+1
                                        // overwrites it at next iteration top
    }

    // --- epilogue: C/D layout col=lane&31, row=(reg&3)+8*(reg>>2)+4*(lane>>5) ---
#pragma unroll
    for (int a = 0; a < 2; ++a) {
        const int ocb = w0 * 64 + a * 32 + 4 * lhi;
#pragma unroll
        for (int reg = 0; reg < 16; ++reg) {
            const int oc = ocb + (reg & 3) + 8 * (reg >> 2);
            const float bv = bias[oc];
            const size_t base = (((size_t)b * OC + oc) * HH + (row0 + pr)) * WW;
            out[base + lane31]      = acc[a][0][reg] + bv;
            out[base + 32 + lane31] = acc[a][1][reg] + bv;
        }
    }
}

extern "C" void kernel_launch(void* const* d_in, const int* in_sizes, int n_in,
                              void* d_out, int out_size, void* d_ws, size_t ws_size,
                              hipStream_t stream) {
    const float* x   = (const float*)d_in[0];
    const int*   idx = (const int*)d_in[1];
    const float* Wc  = (const float*)d_in[2];
    const float* bc  = (const float*)d_in[3];
    float* out  = (float*)d_out;
    ushort* wre = (ushort*)d_ws;   // 294,912 bf16 = 576 KB scratch

    reorder_w<<<128, 256, 0, stream>>>(Wc, wre);    // 128*2304 = 294,912 = |Wc|
    moe_conv_mfma<<<1024, 256, 0, stream>>>(x, idx, wre, bc, out);
}

// Round 6
// 112.212 us; speedup vs baseline: 1.0696x; 1.0696x over previous
//
#include <hip/hip_runtime.h>
#include <hip/hip_bf16.h>

// MoE conv via bf16 MFMA implicit GEMM — ONE mega-block per CU.
// x: [32,64,64,64] f32  idx: [32] i32  Wc: [4,128,64,3,3] f32  bc: [4,128] f32
// out: [32,128,64,64] f32
//
// R4 post-mortem: three different weight paths (LDS-via-VGPR / per-lane global
// / global_load_lds pipe) ALL measured ~42 us -> weights were never the
// bottleneck. Shared cost: 1024 tiny blocks = 4 serial block-generations/CU,
// each re-staging x (2x halo redundancy), 72 barriers/CU, 16:16 LDS:MFMA.
//
// New: grid 256 = exactly 1 block/CU. 512 thr = 8 waves; wave = 1 output row
// x 128 oc x 64 px -> 4x2 accs of mfma_f32_32x32x16_bf16 (128 acc VGPRs; fine
// since LDS caps at 2 waves/SIMD -> 256-VGPR budget, launch_bounds(512,2)).
//   - block generations 4 -> 1 (no re-staging, one ramp/drain)
//   - x staging 10 rows / 8 out rows = 1.25x redundancy (was 2x)
//   - 24 ds_reads feed 32 MFMAs per tap per wave (was 16:16)
//   - barriers per CU 72 -> 17
// Weights: T3/T4 kept — global_load_lds DMA, tap double-buffer, counted
// vmcnt(2) so next-tap loads fly across barriers. T1 XCD swizzle: XCD c owns
// samples 4c..4c+3. T5 setprio around MFMA cluster.
// LDS 84480(xs,10 rows) + 32768(wbuf) + 512(bias) = 117.8 KB (<160; >64 KB
// static OK on gfx950 per 128 KB 8-phase template).
//
// (Round-5 resubmission: R4's bench of this kernel failed with
// GPUAcquisitionTimeout — no data yet.)

#define IC 64
#define OC 128
#define HH 64
#define WW 64

typedef short short8 __attribute__((ext_vector_type(8)));
typedef ushort ushort8 __attribute__((ext_vector_type(8)));
typedef float float16 __attribute__((ext_vector_type(16)));

typedef const __attribute__((address_space(1))) void gas_t;
typedef __attribute__((address_space(3))) void las_t;

static __device__ __forceinline__ ushort f2bf(float v) {
    __hip_bfloat16 h = __float2bfloat16(v);
    return *(ushort*)&h;
}

// ---------------- pre-kernel: reorder + convert weights ----------------
// Block = (e, oc-group of 4). Phase 1: contiguous read of 2304 floats
// (coalesced), bf16 into LDS [ocl][ic*9+tap] with row pad 576->584. Phase 2:
// 288 ushort8 chunks, 8 LDS gathers each, coalesced 16B stores.
// Layout out: [e][tap][ich8][oc128][icl8].
__global__ __launch_bounds__(256)
void reorder_w(const float* __restrict__ Wc, ushort* __restrict__ wout) {
    __shared__ ushort lw[4 * 584];          // 4672 B
    const int t   = threadIdx.x;
    const int e   = blockIdx.x >> 5;        // 0..3
    const int oc0 = (blockIdx.x & 31) * 4;  // 0,4,..,124
    const float* src = Wc + (size_t)(e * 128 + oc0) * 576;
#pragma unroll
    for (int k = 0; k < 9; ++k) {           // 9*256 = 2304 floats
        const int f   = k * 256 + t;
        const int ocl = f / 576;
        const int rem = f - ocl * 576;      // ic*9 + tap
        lw[ocl * 584 + rem] = f2bf(src[f]);
    }
    __syncthreads();
#pragma unroll
    for (int k = 0; k < 2; ++k) {
        const int n = k * 256 + t;          // 0..287 = tap(9) x ich(8) x ocl(4)
        if (n < 288) {
            const int ocl = n & 3, ich = (n >> 2) & 7, tap = n >> 5;
            ushort8 v;
#pragma unroll
            for (int icl = 0; icl < 8; ++icl)
                v[icl] = lw[ocl * 584 + (ich * 8 + icl) * 9 + tap];
            *(ushort8*)(wout +
                ((((size_t)(e * 9 + tap) * 8 + ich) * 128 + oc0 + ocl) * 8)) = v;
        }
    }
}

// ---------------- main kernel ----------------
__global__ __launch_bounds__(512, 2)
void moe_conv_mfma(const float* __restrict__ x, const int* __restrict__ idx,
                   const ushort* __restrict__ wre, const float* __restrict__ bc,
                   float* __restrict__ out) {
    __shared__ __align__(16) ushort xs[10 * 8 * 66 * 8];  // [r][ich][hc][icl] 84480 B
    __shared__ __align__(16) ushort wbuf[2][8192];        // tap dbuf, 2x16 KB
    __shared__ float bias[128];

    const int t = threadIdx.x;

    // T1: XCD c (= lin%8) owns nw in [32c,32c+32) = samples 4c..4c+3, whole.
    const int lin = blockIdx.x;                 // 0..255
    const int nw  = (lin & 7) * 32 + (lin >> 3);
    const int b   = nw >> 3;                    // sample 0..31
    const int rq  = nw & 7;                     // row-block 0..7
    const int row0 = rq * 8;
    const int e    = ((unsigned)idx[b]) & 3;    // hardened expert index

    // --- per-lane MFMA coordinates ---
    const int lane31 = t & 31;
    const int lhi    = (t >> 5) & 1;
    const int wv     = t >> 6;            // 0..7 = output row within block

    const ushort* we = wre + (size_t)e * 9 * 8192;   // e-slice: 73,728 bf16

    // --- issue tap-0 DMA now: flies under the whole x-staging phase ---
    // 16 KB tap slice / 512 threads / 16B = 2 global_load_lds per thread.
    // LDS dest: linear base + t*16 — matches wre order ✓.
#pragma unroll
    for (int i = 0; i < 2; ++i) {
        __builtin_amdgcn_global_load_lds(
            (gas_t*)(we + i * 4096 + t * 8),
            (las_t*)&wbuf[0][i * 4096 + t * 8], 16, 0, 0);
    }

    // --- halo-column zeros (hc = 0, 65) + bias stage ---
    if (t < 320) {  // r(10) x ich(8) x side(2) x q(2)
        const int r = t >> 5, rem = t & 31;
        const int ich = rem >> 2, side = (rem >> 1) & 1, q = rem & 1;
        const int hc = side ? 65 : 0;
        ushort4 z = {0, 0, 0, 0};
        *(ushort4*)&xs[(((r * 8 + ich) * 66 + hc) * 8 + q * 4)] = z;
    } else if (t < 448) {
        bias[t - 320] = bc[e * OC + (t - 320)];
    }

    // --- x staging: fp32 [ic][h][w] -> bf16 [r(10)][ich][hc][icl] ---
    const float* xb = x + (size_t)b * IC * HH * WW;
    {
        const int gc   = t & 63;          // coalesced lane = w
        const int csel = t >> 6;          // 0..7
#pragma unroll
        for (int it = 0; it < 20; ++it) {
            const int combo = it * 8 + csel;       // 0..159 = r(10) x ich(8) x q(2)
            const int r = combo >> 4, rem = combo & 15;
            const int ich = rem >> 1, q = rem & 1;
            const int gr = row0 - 1 + r;
            ushort4 u = {0, 0, 0, 0};
            if ((unsigned)gr < (unsigned)HH) {
                const int ic0 = ich * 8 + q * 4;
                u.x = f2bf(xb[((ic0 + 0) * HH + gr) * WW + gc]);
                u.y = f2bf(xb[((ic0 + 1) * HH + gr) * WW + gc]);
                u.z = f2bf(xb[((ic0 + 2) * HH + gr) * WW + gc]);
                u.w = f2bf(xb[((ic0 + 3) * HH + gr) * WW + gc]);
            }
            *(ushort4*)&xs[(((r * 8 + ich) * 66 + (gc + 1)) * 8 + q * 4)] = u;
        }
    }

    float16 acc[4][2];
#pragma unroll
    for (int g = 0; g < 4; ++g)
#pragma unroll
        for (int cg = 0; cg < 2; ++cg)
#pragma unroll
            for (int r = 0; r < 16; ++r) acc[g][cg][r] = 0.0f;

    // Lane-constant parts of addresses (ushort indices).
    const int xrow  = wv * 4224 + lane31 * 8;       // rr=wv+kh adds kh*4224
    const int abase = lane31 * 8;                   // + ich*1024 + g*256

    // --- 9-tap pipeline: issue tap+1 DMA, counted vmcnt, barrier, MFMA, barrier
#pragma unroll
    for (int tap = 0; tap < 9; ++tap) {
        const int cur = tap & 1;
        if (tap < 8) {
            const ushort* wt = we + (tap + 1) * 8192;
#pragma unroll
            for (int i = 0; i < 2; ++i) {
                __builtin_amdgcn_global_load_lds(
                    (gas_t*)(wt + i * 4096 + t * 8),
                    (las_t*)&wbuf[cur ^ 1][i * 4096 + t * 8], 16, 0, 0);
            }
            // wait own tap-DMAs + all staging (2 newer = tap+1's stay in
            // flight); lgkmcnt(0): staging ds_writes drained (tap 0)
            asm volatile("s_waitcnt vmcnt(2) lgkmcnt(0)" ::: "memory");
        } else {
            asm volatile("s_waitcnt vmcnt(0) lgkmcnt(0)" ::: "memory");
        }
        __builtin_amdgcn_s_barrier();   // tap data + xs visible to all waves

        const int kh = tap / 3;
        const int kw = tap - kh * 3;
        const int xtap = xrow + kh * 4224 + kw * 8;

        __builtin_amdgcn_s_setprio(1);
#pragma unroll
        for (int ks = 0; ks < 4; ++ks) {
            const int ich = ks * 2 + lhi;
            const int xo = xtap + ich * 528;
            const short8 b0 = *(const short8*)&xs[xo];
            const short8 b1 = *(const short8*)&xs[xo + 256];
            const int ao = abase + ich * 1024;
            const short8 a0 = *(const short8*)&wbuf[cur][ao];
            const short8 a1 = *(const short8*)&wbuf[cur][ao + 256];
            const short8 a2 = *(const short8*)&wbuf[cur][ao + 512];
            const short8 a3 = *(const short8*)&wbuf[cur][ao + 768];
            acc[0][0] = __builtin_amdgcn_mfma_f32_32x32x16_bf16(a0, b0, acc[0][0], 0, 0, 0);
            acc[0][1] = __builtin_amdgcn_mfma_f32_32x32x16_bf16(a0, b1, acc[0][1], 0, 0, 0);
            acc[1][0] = __builtin_amdgcn_mfma_f32_32x32x16_bf16(a1, b0, acc[1][0], 0, 0, 0);
            acc[1][1] = __builtin_amdgcn_mfma_f32_32x32x16_bf16(a1, b1, acc[1][1], 0, 0, 0);
            acc[2][0] = __builtin_amdgcn_mfma_f32_32x32x16_bf16(a2, b0, acc[2][0], 0, 0, 0);
            acc[2][1] = __builtin_amdgcn_mfma_f32_32x32x16_bf16(a2, b1, acc[2][1], 0, 0, 0);
            acc[3][0] = __builtin_amdgcn_mfma_f32_32x32x16_bf16(a3, b0, acc[3][0], 0, 0, 0);
            acc[3][1] = __builtin_amdgcn_mfma_f32_32x32x16_bf16(a3, b1, acc[3][1], 0, 0, 0);
        }
        __builtin_amdgcn_s_setprio(0);

        if (tap < 8)
            __builtin_amdgcn_s_barrier();   // wbuf[cur^1] reads of tap-1 done
                                            // before tap+2's DMA overwrites it
    }

    // --- epilogue: C/D layout col=lane&31, row=(reg&3)+8*(reg>>2)+4*(lane>>5) ---
#pragma unroll
    for (int g = 0; g < 4; ++g) {
        const int ocb = g * 32 + 4 * lhi;
#pragma unroll
        for (int reg = 0; reg < 16; ++reg) {
            const int oc = ocb + (reg & 3) + 8 * (reg >> 2);
            const float bv = bias[oc];
            const size_t base = (((size_t)b * OC + oc) * HH + (row0 + wv)) * WW;
            out[base + lane31]      = acc[g][0][reg] + bv;
            out[base + 32 + lane31] = acc[g][1][reg] + bv;
        }
    }
}

extern "C" void kernel_launch(void* const* d_in, const int* in_sizes, int n_in,
                              void* d_out, int out_size, void* d_ws, size_t ws_size,
                              hipStream_t stream) {
    const float* x   = (const float*)d_in[0];
    const int*   idx = (const int*)d_in[1];
    const float* Wc  = (const float*)d_in[2];
    const float* bc  = (const float*)d_in[3];
    float* out  = (float*)d_out;
    ushort* wre = (ushort*)d_ws;   // 294,912 bf16 = 576 KB scratch

    reorder_w<<<128, 256, 0, stream>>>(Wc, wre);    // 128*2304 = 294,912 = |Wc|
    moe_conv_mfma<<<256, 512, 0, stream>>>(x, idx, wre, bc, out);
}